// Round 1
// baseline (74.411 us; speedup 1.0000x reference)
//
#include <hip/hip_runtime.h>

// MultiEmbedding: out[n,s,:] = sum_l weight[l, x[n,l,s], :]
// weight: [L=8, K=1024, D=512] f32, x: [N=8, L=8, S=4096] int (harness gives int32)
// out: [N=8, S=4096, D=512] f32

#define LVL 8
#define KTOK 1024
#define DIM 512
#define SEQ 4096
#define NB 8

__global__ __launch_bounds__(256) void multi_embed_kernel(
    const int* __restrict__ x, const float* __restrict__ w, float* __restrict__ out) {
  const int tid  = threadIdx.x;
  const int row  = blockIdx.x * 2 + (tid >> 7);  // flat (n*SEQ + s)
  const int lane = tid & 127;                    // float4 slot within DIM (128 * 4 = 512)
  const int n = row >> 12;       // row / SEQ
  const int s = row & (SEQ - 1); // row % SEQ

  const int* xp = x + n * (LVL * SEQ) + s;

  float4 acc = make_float4(0.f, 0.f, 0.f, 0.f);
#pragma unroll
  for (int l = 0; l < LVL; ++l) {
    const int idx = xp[l * SEQ];
    const float4* wp =
        reinterpret_cast<const float4*>(w + ((size_t)(l * KTOK + idx)) * DIM);
    const float4 v = wp[lane];
    acc.x += v.x;
    acc.y += v.y;
    acc.z += v.z;
    acc.w += v.w;
  }

  float4* op = reinterpret_cast<float4*>(out + (size_t)row * DIM);
  op[lane] = acc;
}

extern "C" void kernel_launch(void* const* d_in, const int* in_sizes, int n_in,
                              void* d_out, int out_size, void* d_ws, size_t ws_size,
                              hipStream_t stream) {
  const int*   x = (const int*)d_in[0];    // [N, L, S]
  const float* w = (const float*)d_in[1];  // [L, K, D]
  float*     out = (float*)d_out;          // [N, S, D]

  const int rows = NB * SEQ;               // 32768
  dim3 grid(rows / 2);                     // 2 rows per 256-thread block
  dim3 block(256);
  multi_embed_kernel<<<grid, block, 0, stream>>>(x, w, out);
}

// Round 2
// 27.679 us; speedup vs baseline: 2.6883x; 2.6883x over previous
//
#include <hip/hip_runtime.h>

// MultiEmbedding: out[n,s,:] = sum_l weight[l, x[n,l,s], :]
// weight: [L=8, K=1024, D=512] f32, x: [N=8, L=8, S=4096] int32
// out: [N=8, S=4096, D=512] f32
//
// Strategy: split D into 8 chunks of 64 floats. chunk = blockIdx % 8 pins each
// chunk to one XCD (round-robin dispatch), whose 4 MiB L2 then holds that
// chunk's entire weight slice (8*1024*256B = 2 MiB) -> each weight byte is
// fetched from HBM once. Output stored nontemporally so the 64 MB write
// stream doesn't evict the weight slice.

#define LVL 8
#define KTOK 1024
#define DIM 512
#define SEQ 4096
#define NB 8
#define CHUNK 64                 // floats per D-chunk
#define NCHUNK (DIM / CHUNK)     // 8 chunks, one per XCD

typedef float f4 __attribute__((ext_vector_type(4)));

__global__ __launch_bounds__(256) void multi_embed_kernel(
    const int* __restrict__ x, const float* __restrict__ w, float* __restrict__ out) {
  const int tid      = threadIdx.x;
  const int chunk    = blockIdx.x & (NCHUNK - 1);  // XCD-pinned D-chunk
  const int rowgroup = blockIdx.x >> 3;
  const int rlocal   = tid >> 4;                   // 16 rows per block
  const int slot     = tid & 15;                   // float4 slot within chunk
  const int row      = rowgroup * 16 + rlocal;     // flat (n*SEQ + s)
  const int n        = row >> 12;                  // row / SEQ
  const int s        = row & (SEQ - 1);            // row % SEQ
  const int dbase    = chunk * CHUNK + slot * 4;

  const int* xp = x + n * (LVL * SEQ) + s;

  int idx[LVL];
#pragma unroll
  for (int l = 0; l < LVL; ++l) idx[l] = xp[l * SEQ];

  f4 acc = {0.f, 0.f, 0.f, 0.f};
#pragma unroll
  for (int l = 0; l < LVL; ++l) {
    const f4 v = *reinterpret_cast<const f4*>(
        w + ((size_t)(l * KTOK + idx[l])) * DIM + dbase);
    acc += v;
  }

  __builtin_nontemporal_store(
      acc, reinterpret_cast<f4*>(out + (size_t)row * DIM + dbase));
}

extern "C" void kernel_launch(void* const* d_in, const int* in_sizes, int n_in,
                              void* d_out, int out_size, void* d_ws, size_t ws_size,
                              hipStream_t stream) {
  const int*   x = (const int*)d_in[0];    // [N, L, S]
  const float* w = (const float*)d_in[1];  // [L, K, D]
  float*     out = (float*)d_out;          // [N, S, D]

  const int rows   = NB * SEQ;             // 32768
  const int blocks = (rows / 16) * NCHUNK; // 16384
  multi_embed_kernel<<<dim3(blocks), dim3(256), 0, stream>>>(x, w, out);
}